// Round 19
// baseline (164.230 us; speedup 1.0000x reference)
//
#include <hip/hip_runtime.h>
#include <math.h>
#include <stdint.h>

#define H 2048
#define HH (H * H)
#define NB 256
#define NBK 1024                // regions (=buckets) per side
#define RPIX (HH / NBK)         // 4096 pixels per region
#define RLOG 12                 // log2(RPIX)
#define CH 16                   // u16 slots/segment: [0]=count, [1..15]=entries
#define CE 15                   // entry capacity per (bucket,chunk) segment
#define CQUADS 1024             // quads per chunk (4096 samples/side)
#define MAXCH 512               // max chunks (nidx <= 2,097,152)

// ws layout (fast path):
//   [0]       double accum               (8 B)
//   [64]      uint32 hist[2][768]        (6 KiB)   spill histograms
//   [8192]    uint32 hist8[8][1536]      (48 KiB)  8 slices (dst|ref per slice)
//   [65536]   float  table[3][256]       (3 KiB)
//   [131072]  uint32 bits[HH/32]         (512 KiB) membership bitmask
//   [1 MiB]   u16    dlist[1024][MAXCH][16] (16 MiB)
//   [17 MiB]  u16    rlist[1024][MAXCH][16] (16 MiB)
#define OFF_HIST  64
#define OFF_HIST8 8192
#define OFF_TABLE 65536
#define OFF_BITS  131072
#define OFF_DLIST ((size_t)1 << 20)
#define OFF_RLIST ((size_t)17 << 20)
#define WS_FAST   ((size_t)33 << 20)

__global__ void k_init(uint32_t* __restrict__ ws32) {
    int tid = blockIdx.x * blockDim.x + threadIdx.x;
    int stride = gridDim.x * blockDim.x;
    uint4 z = {0u, 0u, 0u, 0u};
    // zero [0, 57344): accum + hist + hist8  (3584 uint4)
    uint4* a = (uint4*)ws32;
    for (int i = tid; i < 3584; i += stride) a[i] = z;
    // zero bits: 32768 uint4
    uint4* b = (uint4*)((char*)ws32 + OFF_BITS);
    for (int i = tid; i < 32768; i += stride) b[i] = z;
}

__device__ __forceinline__ float de_norm255(float x) {
    return fminf(fmaxf((x + 1.0f) * 0.5f, 0.0f), 1.0f) * 255.0f;
}

__device__ __forceinline__ uint32_t bin_of(float v, float m) {
    return (uint32_t)(de_norm255(v) * m);  // in [0,255], trunc==floor
}

#define E4(v, e) ((e) == 0 ? (v).x : (e) == 1 ? (v).y : (e) == 2 ? (v).z : (v).w)

// blockIdx.y: side = y>>1, half = y&1 (each block owns 512 buckets).
// Single-pass partition into fixed per-(bucket,chunk) 32 B segments (count
// embedded), flushed coalesced. 18 KiB LDS -> 8 blocks/CU; grid ~4*nchunk.
__global__ __launch_bounds__(256) void k_bucket(
    const int* __restrict__ i0, const int* __restrict__ i1,
    const int* __restrict__ i2, const int* __restrict__ i3,
    unsigned short* __restrict__ dlist, unsigned short* __restrict__ rlist,
    const float* __restrict__ ref, const float* __restrict__ msrc,
    const float* __restrict__ tgt, const float* __restrict__ mtar,
    uint32_t* __restrict__ hist, uint32_t* __restrict__ bits,
    int nquad, int nchunk) {
    __shared__ __align__(16) unsigned short stag[512 * CH];  // 16 KiB
    __shared__ uint32_t lcnt[512];                           // 2 KiB
    int side = blockIdx.y >> 1;
    int half = blockIdx.y & 1;
    int chunk = blockIdx.x;
    for (int i = threadIdx.x; i < 512; i += 256) lcnt[i] = 0u;
    __syncthreads();
    const int* ia = side ? i2 : i0;
    const int* ib = side ? i3 : i1;
#pragma unroll
    for (int it = 0; it < CQUADS / 256; ++it) {
        int q = chunk * CQUADS + it * 256 + threadIdx.x;
        if (q < nquad) {
            int4 a = ((const int4*)ia)[q];
            int4 b = ((const int4*)ib)[q];
            int p[4] = {a.x * H + b.x, a.y * H + b.y, a.z * H + b.z, a.w * H + b.w};
#pragma unroll
            for (int j = 0; j < 4; ++j) {
                int bk = p[j] >> RLOG;
                if ((bk >> 9) != half) continue;
                int lb = bk & 511;
                uint32_t s = atomicAdd(&lcnt[lb], 1u);
                if (s < CE) {
                    stag[lb * CH + 1 + s] = (unsigned short)(p[j] & (RPIX - 1));
                } else {  // spill: ~1e-6/cell; correct, output-invariant slow path
                    int p0 = p[j];
                    if (side == 0) {
                        float m = msrc[p0];
                        atomicOr(&bits[p0 >> 5], 1u << (p0 & 31));
#pragma unroll
                        for (int c = 0; c < 3; ++c)
                            atomicAdd(&hist[c * NB + bin_of(ref[c * HH + p0], m)], 1u);
                    } else {
                        float m = mtar[p0];
#pragma unroll
                        for (int c = 0; c < 3; ++c)
                            atomicAdd(&hist[768 + c * NB + bin_of(tgt[c * HH + p0], m)], 1u);
                    }
                }
            }
        }
    }
    __syncthreads();
    for (int lb = threadIdx.x; lb < 512; lb += 256)
        stag[lb * CH] = (unsigned short)min(lcnt[lb], (uint32_t)CE);
    __syncthreads();
    // flush: 32 B per bucket segment (2 x uint4)
    unsigned short* glist = side ? rlist : dlist;
    for (int lb = threadIdx.x; lb < 512; lb += 256) {
        int bk = half * 512 + lb;
        const uint4* s4 = (const uint4*)&stag[lb * CH];
        uint4* g4 = (uint4*)(glist + ((size_t)bk * nchunk + chunk) * CH);
        g4[0] = s4[0];
        g4[1] = s4[1];
    }
}

#define PROCESS_QUAD(cw, m4, v0, v1, v2, qi)                                   \
    {                                                                          \
        uint32_t cnts[4] = {cw.x & 0xffffu, cw.x >> 16, cw.y & 0xffffu,        \
                            cw.y >> 16};                                       \
        _Pragma("unroll") for (int e = 0; e < 4; ++e) {                        \
            uint32_t cn = cnts[e];                                             \
            if (!cn) continue;                                                 \
            float mm = E4(m4, e);                                              \
            uint32_t c0 = bin_of(E4(v0, e), mm);                               \
            uint32_t c1 = bin_of(E4(v1, e), mm);                               \
            uint32_t c2 = bin_of(E4(v2, e), mm);                               \
            if (c0) atomicAdd(&s_h[c0], cn); else z0 += cn;                    \
            if (c1) atomicAdd(&s_h[NB + c1], cn); else z1 += cn;               \
            if (c2) atomicAdd(&s_h[2 * NB + c2], cn); else z2 += cn;           \
        }                                                                      \
        if (!side) {                                                           \
            uint32_t nib = (cnts[0] ? 1u : 0u) | (cnts[1] ? 2u : 0u) |         \
                           (cnts[2] ? 4u : 0u) | (cnts[3] ? 8u : 0u);          \
            atomicOr(&s_bits[(qi) >> 3], nib << (((qi) & 7) * 4));             \
        }                                                                      \
    }

// One block per (side, region). Phase A: 2x uint4 segment reads (no serial
// word chain), unpack in registers, guarded atomics. Phase B: 2-quad batches
// with hoisted loads.
__global__ __launch_bounds__(256, 8) void k_bgather(
    const unsigned short* __restrict__ dlist, const unsigned short* __restrict__ rlist,
    const float* __restrict__ ref, const float* __restrict__ msrc,
    const float* __restrict__ tgt, const float* __restrict__ mtar,
    uint32_t* __restrict__ hist8, uint32_t* __restrict__ bits, int nchunk) {
    __shared__ uint32_t s_cnt[RPIX / 2];     // 8 KiB packed 2xu16 counts
    __shared__ uint32_t s_h[3 * NB];         // 3 KiB
    __shared__ uint32_t s_bits[RPIX / 32];   // 128 words
    int bid = blockIdx.x;
    int side = bid >> 10;
    int b = bid & (NBK - 1);
    const float* v = side ? tgt : ref;
    const float* m = side ? mtar : msrc;
    for (int i = threadIdx.x; i < RPIX / 2; i += 256) s_cnt[i] = 0u;
    for (int i = threadIdx.x; i < 3 * NB; i += 256) s_h[i] = 0u;
    if (!side && threadIdx.x < 128) s_bits[threadIdx.x] = 0u;
    __syncthreads();
    // Phase A: wide segment reads, register unpack
    const unsigned short* lb = (side ? rlist : dlist) + (size_t)b * nchunk * CH;
    for (int c = threadIdx.x; c < nchunk; c += 256) {
        const uint4* s4 = (const uint4*)(lb + (size_t)c * CH);
        uint4 A = s4[0];
        uint4 B = s4[1];                     // same 64B line: free
        int cnt = (int)(A.x & 0xffffu);
        uint32_t e[15];
        e[0] = A.x >> 16;
        e[1] = A.y & 0xffffu;  e[2] = A.y >> 16;
        e[3] = A.z & 0xffffu;  e[4] = A.z >> 16;
        e[5] = A.w & 0xffffu;  e[6] = A.w >> 16;
        e[7] = B.x & 0xffffu;  e[8] = B.x >> 16;
        e[9] = B.y & 0xffffu;  e[10] = B.y >> 16;
        e[11] = B.z & 0xffffu; e[12] = B.z >> 16;
        e[13] = B.w & 0xffffu; e[14] = B.w >> 16;
#pragma unroll
        for (int i = 0; i < 15; ++i)
            if (i < cnt)
                atomicAdd(&s_cnt[e[i] >> 1], 1u << ((e[i] & 1) * 16));
    }
    __syncthreads();
    // Phase B: 2-quad batches, hoisted loads
    uint32_t z0 = 0, z1 = 0, z2 = 0;
    int qbase = b * (RPIX / 4);
#pragma unroll
    for (int k = 0; k < 4; k += 2) {
        int qiA = threadIdx.x + k * 256;
        int qiB = qiA + 256;
        uint2 cwA = ((const uint2*)s_cnt)[qiA];
        uint2 cwB = ((const uint2*)s_cnt)[qiB];
        uint32_t hA = cwA.x | cwA.y;
        uint32_t hB = cwB.x | cwB.y;
        int gA = qbase + qiA, gB = qbase + qiB;
        float4 mA, a0, a1, a2, mB, b0, b1, b2;
        if (hA) {
            mA = ((const float4*)m)[gA];
            a0 = ((const float4*)(v))[gA];
            a1 = ((const float4*)(v + HH))[gA];
            a2 = ((const float4*)(v + 2 * HH))[gA];
        }
        if (hB) {
            mB = ((const float4*)m)[gB];
            b0 = ((const float4*)(v))[gB];
            b1 = ((const float4*)(v + HH))[gB];
            b2 = ((const float4*)(v + 2 * HH))[gB];
        }
        if (hA) PROCESS_QUAD(cwA, mA, a0, a1, a2, qiA);
        if (hB) PROCESS_QUAD(cwB, mB, b0, b1, b2, qiB);
    }
    if (z0) atomicAdd(&s_h[0], z0);
    if (z1) atomicAdd(&s_h[NB], z1);
    if (z2) atomicAdd(&s_h[2 * NB], z2);
    __syncthreads();
    uint32_t* hs = hist8 + (bid & 7) * 1536 + (side ? 768 : 0);
    for (int i = threadIdx.x; i < 3 * NB; i += 256)
        if (s_h[i]) atomicAdd(&hs[i], s_h[i]);
    if (!side && threadIdx.x < 128) {
        uint32_t* gb = bits + b * (RPIX / 32);
        uint32_t sb = s_bits[threadIdx.x];
        gb[threadIdx.x] = gb[threadIdx.x] | sb;  // block-exclusive; keeps spill bits
    }
}

// Monolithic fallback (any ws): gather floats via LLC + bits mask.
__global__ void k_hist_fb(const float* __restrict__ tgt, const float* __restrict__ ref,
                          const float* __restrict__ msrc, const float* __restrict__ mtar,
                          const int* __restrict__ i0, const int* __restrict__ i1,
                          const int* __restrict__ i2, const int* __restrict__ i3,
                          uint32_t* __restrict__ hist, uint32_t* __restrict__ bits,
                          int nidx) {
    __shared__ uint32_t lh[6 * NB];
    for (int i = threadIdx.x; i < 6 * NB; i += blockDim.x) lh[i] = 0u;
    __syncthreads();
    int stride = gridDim.x * blockDim.x;
    for (int k = blockIdx.x * blockDim.x + threadIdx.x; k < nidx; k += stride) {
        int pa = i0[k] * H + i1[k];
        int pb = i2[k] * H + i3[k];
        float ms = msrc[pa];
        float mt = mtar[pb];
        atomicOr(&bits[pa >> 5], 1u << (pa & 31));
#pragma unroll
        for (int c = 0; c < 3; ++c) {
            atomicAdd(&lh[c * NB + bin_of(ref[c * HH + pa], ms)], 1u);
            atomicAdd(&lh[(3 + c) * NB + bin_of(tgt[c * HH + pb], mt)], 1u);
        }
    }
    __syncthreads();
    for (int i = threadIdx.x; i < 6 * NB; i += blockDim.x)
        if (lh[i]) atomicAdd(&hist[i], lh[i]);   // lh layout == hist layout
}

// 3 blocks (one per channel) x 256 threads; sums spill hist + 8 slices.
__global__ void k_table(const uint32_t* __restrict__ hist,
                        const uint32_t* __restrict__ hist8,
                        float* __restrict__ table) {
    int c = blockIdx.x;
    int t = threadIdx.x;
    __shared__ uint32_t cdd[NB], crr[NB];
    __shared__ float r[NB], a[NB];
    uint32_t sd = hist[c * NB + t];
    uint32_t sr = hist[768 + c * NB + t];
#pragma unroll
    for (int x = 0; x < 8; ++x) {
        sd += hist8[x * 1536 + c * NB + t];
        sr += hist8[x * 1536 + 768 + c * NB + t];
    }
    cdd[t] = sd;
    crr[t] = sr;
    __syncthreads();
    if (t == 0) {
        uint32_t s = 0;
        for (int i = 0; i < NB; ++i) { s += cdd[i]; cdd[i] = s; }
        s = 0;
        for (int i = 0; i < NB; ++i) { s += crr[i]; crr[i] = s; }
    }
    __syncthreads();
    float totd = (float)cdd[NB - 1];
    float totr = (float)crr[NB - 1];
    r[t] = (float)cdd[t] / totd;
    a[t] = (float)crr[t] / totr;
    __syncthreads();
    float out;
    if (t == 0) {
        out = 0.0f;
    } else if (t == NB - 1) {
        out = (float)(NB - 1);
    } else {
        float ri = r[t];
        int j = -1;
        for (int jj = 0; jj < NB - 1; ++jj) {
            if (ri >= a[jj] && ri <= a[jj + 1]) { j = jj; break; }
        }
        out = (j >= 0) ? (float)(j + 1) : (float)t;
    }
    table[c * NB + t] = out;
}

// float4-vectorized loss; membership from bits; table in LDS.
__global__ void k_loss(const float* __restrict__ inp, const float* __restrict__ ref,
                       const float* __restrict__ msrc, const uint32_t* __restrict__ bits,
                       const float* __restrict__ table, double* __restrict__ accum) {
    __shared__ float tl[3 * NB];
    for (int i = threadIdx.x; i < 3 * NB; i += blockDim.x) tl[i] = table[i];
    __syncthreads();
    float part = 0.0f;
    int stride = gridDim.x * blockDim.x;
    for (int q = blockIdx.x * blockDim.x + threadIdx.x; q < HH / 4; q += stride) {
        float4 m4 = ((const float4*)msrc)[q];
        uint32_t nib = bits[q >> 3] >> ((q & 7) * 4);
#pragma unroll
        for (int c = 0; c < 3; ++c) {
            float4 iv = ((const float4*)(inp + c * HH))[q];
            float4 rv = ((const float4*)(ref + c * HH))[q];
#pragma unroll
            for (int e = 0; e < 4; ++e) {
                float m = E4(m4, e);
                float im = de_norm255(E4(iv, e)) * m;
                float r = de_norm255(E4(rv, e)) * m;
                float match;
                if ((nib >> e) & 1u)
                    match = tl[c * NB + (int)fminf(fmaxf(r, 0.0f), 255.0f)];
                else
                    match = r;
                part += fabsf(im - match);
            }
        }
    }
#pragma unroll
    for (int off = 32; off > 0; off >>= 1) part += __shfl_down(part, off);
    __shared__ float wsum[4];
    int lane = threadIdx.x & 63;
    int wid = threadIdx.x >> 6;
    if (lane == 0) wsum[wid] = part;
    __syncthreads();
    if (threadIdx.x == 0)
        atomicAdd(accum, (double)(wsum[0] + wsum[1] + wsum[2] + wsum[3]));
}

__global__ void k_final(const double* __restrict__ accum, float* __restrict__ out) {
    if (threadIdx.x == 0 && blockIdx.x == 0)
        out[0] = (float)(*accum / (double)(3.0 * (double)HH));
}

extern "C" void kernel_launch(void* const* d_in, const int* in_sizes, int n_in,
                              void* d_out, int out_size, void* d_ws, size_t ws_size,
                              hipStream_t stream) {
    const float* input  = (const float*)d_in[0];
    const float* target = (const float*)d_in[1];
    const float* ref    = (const float*)d_in[2];
    const float* msrc   = (const float*)d_in[3];
    const float* mtar   = (const float*)d_in[4];
    const int* i0 = (const int*)d_in[5];
    const int* i1 = (const int*)d_in[6];
    const int* i2 = (const int*)d_in[7];
    const int* i3 = (const int*)d_in[8];
    int nidx = in_sizes[5];

    char* ws = (char*)d_ws;
    double*   accum = (double*)(ws);
    uint32_t* hist  = (uint32_t*)(ws + OFF_HIST);
    uint32_t* hist8 = (uint32_t*)(ws + OFF_HIST8);
    float*    table = (float*)(ws + OFF_TABLE);
    uint32_t* bits  = (uint32_t*)(ws + OFF_BITS);

    k_init<<<512, 256, 0, stream>>>((uint32_t*)ws);

    int nquad = nidx / 4;
    int nchunk = (nquad + CQUADS - 1) / CQUADS;
    if (ws_size >= WS_FAST && (nidx & 3) == 0 && nchunk <= MAXCH) {
        unsigned short* dlist = (unsigned short*)(ws + OFF_DLIST);
        unsigned short* rlist = (unsigned short*)(ws + OFF_RLIST);
        dim3 bgrid(nchunk, 4);
        k_bucket<<<bgrid, 256, 0, stream>>>(
            i0, i1, i2, i3, dlist, rlist, ref, msrc, target, mtar,
            hist, bits, nquad, nchunk);
        k_bgather<<<2048, 256, 0, stream>>>(dlist, rlist, ref, msrc, target, mtar,
                                            hist8, bits, nchunk);
    } else {
        k_hist_fb<<<2048, 256, 0, stream>>>(target, ref, msrc, mtar, i0, i1, i2, i3,
                                            hist, bits, nidx);
    }
    k_table<<<3, 256, 0, stream>>>(hist, hist8, table);
    k_loss<<<4096, 256, 0, stream>>>(input, ref, msrc, bits, table, accum);
    k_final<<<1, 64, 0, stream>>>(accum, (float*)d_out);
}

// Round 20
// 141.762 us; speedup vs baseline: 1.1585x; 1.1585x over previous
//
#include <hip/hip_runtime.h>
#include <math.h>
#include <stdint.h>

#define H 2048
#define HH (H * H)
#define NB 256
#define NBK 1024                // regions (=buckets) per side
#define RPIX (HH / NBK)         // 4096 pixels per region
#define RLOG 12                 // log2(RPIX)
#define CH 16                   // u16 slots/segment: [0]=count, [1..15]=entries
#define CE 15                   // entry capacity per (bucket,chunk) segment
#define CQUADS 1024             // quads per chunk (4096 samples/side)
#define MAXCH 512               // max chunks (nidx <= 2,097,152)

// ws layout (fast path):
//   [0]       double accum               (8 B)
//   [64]      uint32 hist[2][768]        (6 KiB)   spill histograms
//   [8192]    uint32 hist8[8][1536]      (48 KiB)  8 slices (dst|ref per slice)
//   [65536]   float  table[3][256]       (3 KiB)
//   [131072]  uint32 bits[HH/32]         (512 KiB) membership bitmask
//   [1 MiB]   u16    dlist[1024][MAXCH][16] (16 MiB)
//   [17 MiB]  u16    rlist[1024][MAXCH][16] (16 MiB)
#define OFF_HIST  64
#define OFF_HIST8 8192
#define OFF_TABLE 65536
#define OFF_BITS  131072
#define OFF_DLIST ((size_t)1 << 20)
#define OFF_RLIST ((size_t)17 << 20)
#define WS_FAST   ((size_t)33 << 20)

__global__ void k_init(uint32_t* __restrict__ ws32) {
    int tid = blockIdx.x * blockDim.x + threadIdx.x;
    int stride = gridDim.x * blockDim.x;
    uint4 z = {0u, 0u, 0u, 0u};
    // zero [0, 57344): accum + hist + hist8  (3584 uint4)
    uint4* a = (uint4*)ws32;
    for (int i = tid; i < 3584; i += stride) a[i] = z;
    // zero bits: 32768 uint4
    uint4* b = (uint4*)((char*)ws32 + OFF_BITS);
    for (int i = tid; i < 32768; i += stride) b[i] = z;
}

__device__ __forceinline__ float de_norm255(float x) {
    return fminf(fmaxf((x + 1.0f) * 0.5f, 0.0f), 1.0f) * 255.0f;
}

__device__ __forceinline__ uint32_t bin_of(float v, float m) {
    return (uint32_t)(de_norm255(v) * m);  // in [0,255], trunc==floor
}

#define E4(v, e) ((e) == 0 ? (v).x : (e) == 1 ? (v).y : (e) == 2 ? (v).z : (v).w)

// blockIdx.y: side = y>>1, half = y&1 (each block owns 512 buckets).
// Single-pass partition into fixed per-(bucket,chunk) 32 B segments (count
// embedded), flushed coalesced. 18 KiB LDS -> 8 blocks/CU; grid ~4*nchunk.
__global__ __launch_bounds__(256) void k_bucket(
    const int* __restrict__ i0, const int* __restrict__ i1,
    const int* __restrict__ i2, const int* __restrict__ i3,
    unsigned short* __restrict__ dlist, unsigned short* __restrict__ rlist,
    const float* __restrict__ ref, const float* __restrict__ msrc,
    const float* __restrict__ tgt, const float* __restrict__ mtar,
    uint32_t* __restrict__ hist, uint32_t* __restrict__ bits,
    int nquad, int nchunk) {
    __shared__ __align__(16) unsigned short stag[512 * CH];  // 16 KiB
    __shared__ uint32_t lcnt[512];                           // 2 KiB
    int side = blockIdx.y >> 1;
    int half = blockIdx.y & 1;
    int chunk = blockIdx.x;
    for (int i = threadIdx.x; i < 512; i += 256) lcnt[i] = 0u;
    __syncthreads();
    const int* ia = side ? i2 : i0;
    const int* ib = side ? i3 : i1;
#pragma unroll
    for (int it = 0; it < CQUADS / 256; ++it) {
        int q = chunk * CQUADS + it * 256 + threadIdx.x;
        if (q < nquad) {
            int4 a = ((const int4*)ia)[q];
            int4 b = ((const int4*)ib)[q];
            int p[4] = {a.x * H + b.x, a.y * H + b.y, a.z * H + b.z, a.w * H + b.w};
#pragma unroll
            for (int j = 0; j < 4; ++j) {
                int bk = p[j] >> RLOG;
                if ((bk >> 9) != half) continue;
                int lb = bk & 511;
                uint32_t s = atomicAdd(&lcnt[lb], 1u);
                if (s < CE) {
                    stag[lb * CH + 1 + s] = (unsigned short)(p[j] & (RPIX - 1));
                } else {  // spill: ~1e-6/cell; correct, output-invariant slow path
                    int p0 = p[j];
                    if (side == 0) {
                        float m = msrc[p0];
                        atomicOr(&bits[p0 >> 5], 1u << (p0 & 31));
#pragma unroll
                        for (int c = 0; c < 3; ++c)
                            atomicAdd(&hist[c * NB + bin_of(ref[c * HH + p0], m)], 1u);
                    } else {
                        float m = mtar[p0];
#pragma unroll
                        for (int c = 0; c < 3; ++c)
                            atomicAdd(&hist[768 + c * NB + bin_of(tgt[c * HH + p0], m)], 1u);
                    }
                }
            }
        }
    }
    __syncthreads();
    for (int lb = threadIdx.x; lb < 512; lb += 256)
        stag[lb * CH] = (unsigned short)min(lcnt[lb], (uint32_t)CE);
    __syncthreads();
    // flush: 32 B per bucket segment (2 x uint4)
    unsigned short* glist = side ? rlist : dlist;
    for (int lb = threadIdx.x; lb < 512; lb += 256) {
        int bk = half * 512 + lb;
        const uint4* s4 = (const uint4*)&stag[lb * CH];
        uint4* g4 = (uint4*)(glist + ((size_t)bk * nchunk + chunk) * CH);
        g4[0] = s4[0];
        g4[1] = s4[1];
    }
}

#define PROCESS_QUAD(cw, m4, v0, v1, v2, qi)                                   \
    {                                                                          \
        uint32_t cnts[4] = {cw.x & 0xffffu, cw.x >> 16, cw.y & 0xffffu,        \
                            cw.y >> 16};                                       \
        _Pragma("unroll") for (int e = 0; e < 4; ++e) {                        \
            uint32_t cn = cnts[e];                                             \
            if (!cn) continue;                                                 \
            float mm = E4(m4, e);                                              \
            uint32_t c0 = bin_of(E4(v0, e), mm);                               \
            uint32_t c1 = bin_of(E4(v1, e), mm);                               \
            uint32_t c2 = bin_of(E4(v2, e), mm);                               \
            if (c0) atomicAdd(&s_h[c0], cn); else z0 += cn;                    \
            if (c1) atomicAdd(&s_h[NB + c1], cn); else z1 += cn;               \
            if (c2) atomicAdd(&s_h[2 * NB + c2], cn); else z2 += cn;           \
        }                                                                      \
        if (!side) {                                                           \
            uint32_t nib = (cnts[0] ? 1u : 0u) | (cnts[1] ? 2u : 0u) |         \
                           (cnts[2] ? 4u : 0u) | (cnts[3] ? 8u : 0u);          \
            atomicOr(&s_bits[(qi) >> 3], nib << (((qi) & 7) * 4));             \
        }                                                                      \
    }

// One block per (side, region). Phase A: 2x uint4 segment reads (no serial
// word chain), unpack in registers, guarded atomics. Phase B: 2-quad batches
// with hoisted loads.
__global__ __launch_bounds__(256, 8) void k_bgather(
    const unsigned short* __restrict__ dlist, const unsigned short* __restrict__ rlist,
    const float* __restrict__ ref, const float* __restrict__ msrc,
    const float* __restrict__ tgt, const float* __restrict__ mtar,
    uint32_t* __restrict__ hist8, uint32_t* __restrict__ bits, int nchunk) {
    __shared__ uint32_t s_cnt[RPIX / 2];     // 8 KiB packed 2xu16 counts
    __shared__ uint32_t s_h[3 * NB];         // 3 KiB
    __shared__ uint32_t s_bits[RPIX / 32];   // 128 words
    int bid = blockIdx.x;
    int side = bid >> 10;
    int b = bid & (NBK - 1);
    const float* v = side ? tgt : ref;
    const float* m = side ? mtar : msrc;
    for (int i = threadIdx.x; i < RPIX / 2; i += 256) s_cnt[i] = 0u;
    for (int i = threadIdx.x; i < 3 * NB; i += 256) s_h[i] = 0u;
    if (!side && threadIdx.x < 128) s_bits[threadIdx.x] = 0u;
    __syncthreads();
    // Phase A: wide segment reads, register unpack
    const unsigned short* lb = (side ? rlist : dlist) + (size_t)b * nchunk * CH;
    for (int c = threadIdx.x; c < nchunk; c += 256) {
        const uint4* s4 = (const uint4*)(lb + (size_t)c * CH);
        uint4 A = s4[0];
        uint4 B = s4[1];                     // same 64B line: free
        int cnt = (int)(A.x & 0xffffu);
        uint32_t e[15];
        e[0] = A.x >> 16;
        e[1] = A.y & 0xffffu;  e[2] = A.y >> 16;
        e[3] = A.z & 0xffffu;  e[4] = A.z >> 16;
        e[5] = A.w & 0xffffu;  e[6] = A.w >> 16;
        e[7] = B.x & 0xffffu;  e[8] = B.x >> 16;
        e[9] = B.y & 0xffffu;  e[10] = B.y >> 16;
        e[11] = B.z & 0xffffu; e[12] = B.z >> 16;
        e[13] = B.w & 0xffffu; e[14] = B.w >> 16;
#pragma unroll
        for (int i = 0; i < 15; ++i)
            if (i < cnt)
                atomicAdd(&s_cnt[e[i] >> 1], 1u << ((e[i] & 1) * 16));
    }
    __syncthreads();
    // Phase B: 2-quad batches, hoisted loads
    uint32_t z0 = 0, z1 = 0, z2 = 0;
    int qbase = b * (RPIX / 4);
#pragma unroll
    for (int k = 0; k < 4; k += 2) {
        int qiA = threadIdx.x + k * 256;
        int qiB = qiA + 256;
        uint2 cwA = ((const uint2*)s_cnt)[qiA];
        uint2 cwB = ((const uint2*)s_cnt)[qiB];
        uint32_t hA = cwA.x | cwA.y;
        uint32_t hB = cwB.x | cwB.y;
        int gA = qbase + qiA, gB = qbase + qiB;
        float4 mA, a0, a1, a2, mB, b0, b1, b2;
        if (hA) {
            mA = ((const float4*)m)[gA];
            a0 = ((const float4*)(v))[gA];
            a1 = ((const float4*)(v + HH))[gA];
            a2 = ((const float4*)(v + 2 * HH))[gA];
        }
        if (hB) {
            mB = ((const float4*)m)[gB];
            b0 = ((const float4*)(v))[gB];
            b1 = ((const float4*)(v + HH))[gB];
            b2 = ((const float4*)(v + 2 * HH))[gB];
        }
        if (hA) PROCESS_QUAD(cwA, mA, a0, a1, a2, qiA);
        if (hB) PROCESS_QUAD(cwB, mB, b0, b1, b2, qiB);
    }
    if (z0) atomicAdd(&s_h[0], z0);
    if (z1) atomicAdd(&s_h[NB], z1);
    if (z2) atomicAdd(&s_h[2 * NB], z2);
    __syncthreads();
    uint32_t* hs = hist8 + (bid & 7) * 1536 + (side ? 768 : 0);
    for (int i = threadIdx.x; i < 3 * NB; i += 256)
        if (s_h[i]) atomicAdd(&hs[i], s_h[i]);
    if (!side && threadIdx.x < 128) {
        uint32_t* gb = bits + b * (RPIX / 32);
        uint32_t sb = s_bits[threadIdx.x];
        gb[threadIdx.x] = gb[threadIdx.x] | sb;  // block-exclusive; keeps spill bits
    }
}

// Monolithic fallback (any ws): gather floats via LLC + bits mask.
__global__ void k_hist_fb(const float* __restrict__ tgt, const float* __restrict__ ref,
                          const float* __restrict__ msrc, const float* __restrict__ mtar,
                          const int* __restrict__ i0, const int* __restrict__ i1,
                          const int* __restrict__ i2, const int* __restrict__ i3,
                          uint32_t* __restrict__ hist, uint32_t* __restrict__ bits,
                          int nidx) {
    __shared__ uint32_t lh[6 * NB];
    for (int i = threadIdx.x; i < 6 * NB; i += blockDim.x) lh[i] = 0u;
    __syncthreads();
    int stride = gridDim.x * blockDim.x;
    for (int k = blockIdx.x * blockDim.x + threadIdx.x; k < nidx; k += stride) {
        int pa = i0[k] * H + i1[k];
        int pb = i2[k] * H + i3[k];
        float ms = msrc[pa];
        float mt = mtar[pb];
        atomicOr(&bits[pa >> 5], 1u << (pa & 31));
#pragma unroll
        for (int c = 0; c < 3; ++c) {
            atomicAdd(&lh[c * NB + bin_of(ref[c * HH + pa], ms)], 1u);
            atomicAdd(&lh[(3 + c) * NB + bin_of(tgt[c * HH + pb], mt)], 1u);
        }
    }
    __syncthreads();
    for (int i = threadIdx.x; i < 6 * NB; i += blockDim.x)
        if (lh[i]) atomicAdd(&hist[i], lh[i]);   // lh layout == hist layout
}

// 3 blocks (one per channel) x 256 threads; sums spill hist + 8 slices.
__global__ void k_table(const uint32_t* __restrict__ hist,
                        const uint32_t* __restrict__ hist8,
                        float* __restrict__ table) {
    int c = blockIdx.x;
    int t = threadIdx.x;
    __shared__ uint32_t cdd[NB], crr[NB];
    __shared__ float r[NB], a[NB];
    uint32_t sd = hist[c * NB + t];
    uint32_t sr = hist[768 + c * NB + t];
#pragma unroll
    for (int x = 0; x < 8; ++x) {
        sd += hist8[x * 1536 + c * NB + t];
        sr += hist8[x * 1536 + 768 + c * NB + t];
    }
    cdd[t] = sd;
    crr[t] = sr;
    __syncthreads();
    if (t == 0) {
        uint32_t s = 0;
        for (int i = 0; i < NB; ++i) { s += cdd[i]; cdd[i] = s; }
        s = 0;
        for (int i = 0; i < NB; ++i) { s += crr[i]; crr[i] = s; }
    }
    __syncthreads();
    float totd = (float)cdd[NB - 1];
    float totr = (float)crr[NB - 1];
    r[t] = (float)cdd[t] / totd;
    a[t] = (float)crr[t] / totr;
    __syncthreads();
    float out;
    if (t == 0) {
        out = 0.0f;
    } else if (t == NB - 1) {
        out = (float)(NB - 1);
    } else {
        float ri = r[t];
        int j = -1;
        for (int jj = 0; jj < NB - 1; ++jj) {
            if (ri >= a[jj] && ri <= a[jj + 1]) { j = jj; break; }
        }
        out = (j >= 0) ? (float)(j + 1) : (float)t;
    }
    table[c * NB + t] = out;
}

// float4-vectorized loss; membership from bits; table in LDS.
__global__ void k_loss(const float* __restrict__ inp, const float* __restrict__ ref,
                       const float* __restrict__ msrc, const uint32_t* __restrict__ bits,
                       const float* __restrict__ table, double* __restrict__ accum) {
    __shared__ float tl[3 * NB];
    for (int i = threadIdx.x; i < 3 * NB; i += blockDim.x) tl[i] = table[i];
    __syncthreads();
    float part = 0.0f;
    int stride = gridDim.x * blockDim.x;
    for (int q = blockIdx.x * blockDim.x + threadIdx.x; q < HH / 4; q += stride) {
        float4 m4 = ((const float4*)msrc)[q];
        uint32_t nib = bits[q >> 3] >> ((q & 7) * 4);
#pragma unroll
        for (int c = 0; c < 3; ++c) {
            float4 iv = ((const float4*)(inp + c * HH))[q];
            float4 rv = ((const float4*)(ref + c * HH))[q];
#pragma unroll
            for (int e = 0; e < 4; ++e) {
                float m = E4(m4, e);
                float im = de_norm255(E4(iv, e)) * m;
                float r = de_norm255(E4(rv, e)) * m;
                float match;
                if ((nib >> e) & 1u)
                    match = tl[c * NB + (int)fminf(fmaxf(r, 0.0f), 255.0f)];
                else
                    match = r;
                part += fabsf(im - match);
            }
        }
    }
#pragma unroll
    for (int off = 32; off > 0; off >>= 1) part += __shfl_down(part, off);
    __shared__ float wsum[4];
    int lane = threadIdx.x & 63;
    int wid = threadIdx.x >> 6;
    if (lane == 0) wsum[wid] = part;
    __syncthreads();
    if (threadIdx.x == 0)
        atomicAdd(accum, (double)(wsum[0] + wsum[1] + wsum[2] + wsum[3]));
}

__global__ void k_final(const double* __restrict__ accum, float* __restrict__ out) {
    if (threadIdx.x == 0 && blockIdx.x == 0)
        out[0] = (float)(*accum / (double)(3.0 * (double)HH));
}

extern "C" void kernel_launch(void* const* d_in, const int* in_sizes, int n_in,
                              void* d_out, int out_size, void* d_ws, size_t ws_size,
                              hipStream_t stream) {
    const float* input  = (const float*)d_in[0];
    const float* target = (const float*)d_in[1];
    const float* ref    = (const float*)d_in[2];
    const float* msrc   = (const float*)d_in[3];
    const float* mtar   = (const float*)d_in[4];
    const int* i0 = (const int*)d_in[5];
    const int* i1 = (const int*)d_in[6];
    const int* i2 = (const int*)d_in[7];
    const int* i3 = (const int*)d_in[8];
    int nidx = in_sizes[5];

    char* ws = (char*)d_ws;
    double*   accum = (double*)(ws);
    uint32_t* hist  = (uint32_t*)(ws + OFF_HIST);
    uint32_t* hist8 = (uint32_t*)(ws + OFF_HIST8);
    float*    table = (float*)(ws + OFF_TABLE);
    uint32_t* bits  = (uint32_t*)(ws + OFF_BITS);

    k_init<<<512, 256, 0, stream>>>((uint32_t*)ws);

    int nquad = nidx / 4;
    int nchunk = (nquad + CQUADS - 1) / CQUADS;
    if (ws_size >= WS_FAST && (nidx & 3) == 0 && nchunk <= MAXCH) {
        unsigned short* dlist = (unsigned short*)(ws + OFF_DLIST);
        unsigned short* rlist = (unsigned short*)(ws + OFF_RLIST);
        dim3 bgrid(nchunk, 4);
        k_bucket<<<bgrid, 256, 0, stream>>>(
            i0, i1, i2, i3, dlist, rlist, ref, msrc, target, mtar,
            hist, bits, nquad, nchunk);
        k_bgather<<<2048, 256, 0, stream>>>(dlist, rlist, ref, msrc, target, mtar,
                                            hist8, bits, nchunk);
    } else {
        k_hist_fb<<<2048, 256, 0, stream>>>(target, ref, msrc, mtar, i0, i1, i2, i3,
                                            hist, bits, nidx);
    }
    k_table<<<3, 256, 0, stream>>>(hist, hist8, table);
    k_loss<<<2048, 256, 0, stream>>>(input, ref, msrc, bits, table, accum);
    k_final<<<1, 64, 0, stream>>>(accum, (float*)d_out);
}